// Round 9
// baseline (1784.635 us; speedup 1.0000x reference)
//
#include <hip/hip_runtime.h>

#define N_NODES  80000
#define N_EDGES  1280000
#define N_GRAPHS 512
#define DIM      64
#define NCLS     10

#define ETILE    8192
#define NTILE    157      // ceil(N_EDGES / ETILE)
#define NCB      625      // N_NODES / 128 dst-buckets of 128 nodes
#define CBPAD    640

typedef short short8f __attribute__((ext_vector_type(8)));   // 8 bf16 (4 VGPRs)
typedef float float4f __attribute__((ext_vector_type(4)));   // 4 fp32 acc

static __device__ __forceinline__ unsigned short f2bf(float f) {
    unsigned u = __float_as_uint(f);
    unsigned r = (u + 0x7FFFu + ((u >> 16) & 1u)) >> 16;   // RNE
    return (unsigned short)r;
}
static __device__ __forceinline__ float bf_lo(unsigned v) { return __uint_as_float(v << 16); }
static __device__ __forceinline__ float bf_hi(unsigned v) { return __uint_as_float(v & 0xFFFF0000u); }

// ---------- Pass A: per-tile histogram over dst-buckets (no global atomics)
__global__ __launch_bounds__(256) void k_hist(const int* __restrict__ ei,
                                              int* __restrict__ hmat) {
    __shared__ int hist[NCB];
    int tile = blockIdx.x, t = threadIdx.x;
    for (int i = t; i < NCB; i += 256) hist[i] = 0;
    __syncthreads();
    int base = tile * ETILE;
    int end = base + ETILE; if (end > N_EDGES) end = N_EDGES;
    for (int i = base + t; i < end; i += 256)
        atomicAdd(&hist[ei[N_EDGES + i] >> 7], 1);
    __syncthreads();
    for (int i = t; i < NCB; i += 256) hmat[tile * CBPAD + i] = hist[i];
}

// ---------- Pass B1: per-bucket scan across tiles -> within-bucket offsets
__global__ __launch_bounds__(256) void k_scanT(const int* __restrict__ hmat,
        int* __restrict__ obase, int* __restrict__ btot) {
    __shared__ int sa[256], sb[256];
    int b = blockIdx.x, t = threadIdx.x;
    int v = (t < NTILE) ? hmat[t * CBPAD + b] : 0;
    sa[t] = v; __syncthreads();
    int* sp = sa; int* dp = sb;
    for (int off = 1; off < 256; off <<= 1) {
        dp[t] = sp[t] + ((t >= off) ? sp[t - off] : 0);
        __syncthreads();
        int* tmp = sp; sp = dp; dp = tmp;
    }
    int incl = sp[t];
    if (t < NTILE) obase[t * CBPAD + b] = incl - v;
    if (t == NTILE - 1) btot[b] = incl;
}

// ---------- Pass B2: scan 625 bucket totals -> bucket bases
__global__ __launch_bounds__(256) void k_scanB(const int* __restrict__ btot,
        int* __restrict__ bucketbase) {
    __shared__ int sdat[256];
    int t = threadIdx.x, run = 0;
    for (int c = 0; c < 3; ++c) {
        int i = c * 256 + t;
        int v = (i < NCB) ? btot[i] : 0;
        sdat[t] = v; __syncthreads();
        for (int off = 1; off < 256; off <<= 1) {
            int u = (t >= off) ? sdat[t - off] : 0;
            __syncthreads();
            sdat[t] += u;
            __syncthreads();
        }
        if (i < NCB) bucketbase[i] = run + sdat[t] - v;
        run += sdat[255];
        __syncthreads();
    }
    if (t == 0) bucketbase[NCB] = N_EDGES;
}

// ---------- Pass C: scatter into bucket-sorted ebuf (deterministic runs)
// pack: src:17 bits | (dst&127)<<17
__global__ __launch_bounds__(256) void k_scatter(const int* __restrict__ ei,
        const int* __restrict__ obase, const int* __restrict__ bucketbase,
        int* __restrict__ ebuf) {
    __shared__ int cur[NCB];
    int tile = blockIdx.x, t = threadIdx.x;
    for (int i = t; i < NCB; i += 256)
        cur[i] = bucketbase[i] + obase[tile * CBPAD + i];
    __syncthreads();
    int base = tile * ETILE;
    int end = base + ETILE; if (end > N_EDGES) end = N_EDGES;
    for (int i = base + t; i < end; i += 256) {
        int s = ei[i], d = ei[N_EDGES + i];
        int p = atomicAdd(&cur[d >> 7], 1);
        ebuf[p] = s | ((d & 127) << 17);
    }
}

// ---------- Pass D: within-bucket counting sort by src>>9 -> ebuf2
// (ascending-src processing order = L2-friendly sweep of the X table)
__global__ __launch_bounds__(256) void k_sortb(const int* __restrict__ ebuf,
        const int* __restrict__ bucketbase, int* __restrict__ ebuf2) {
    __shared__ int cnt[160];
    __shared__ int sa[256], sb[256];
    int b = blockIdx.x, t = threadIdx.x;
    int s = bucketbase[b], e = bucketbase[b + 1];
    if (t < 160) cnt[t] = 0;
    __syncthreads();
    for (int i = s + t; i < e; i += 256)
        atomicAdd(&cnt[(ebuf[i] & 0x1FFFF) >> 9], 1);
    __syncthreads();
    int v0 = (t < 160) ? cnt[t] : 0;
    sa[t] = v0; __syncthreads();
    int* sp = sa; int* dp = sb;
    for (int off = 1; off < 256; off <<= 1) {
        dp[t] = sp[t] + ((t >= off) ? sp[t - off] : 0);
        __syncthreads();
        int* tmp = sp; sp = dp; dp = tmp;
    }
    if (t < 160) cnt[t] = s + sp[t] - v0;   // global write cursors
    __syncthreads();
    for (int i = s + t; i < e; i += 256) {
        int pk = ebuf[i];
        int p = atomicAdd(&cnt[(pk & 0x1FFFF) >> 9], 1);
        ebuf2[p] = pk;
    }
}

// ---------- prep: cast x -> bf16 (blocks 0..4999) + pack W into MFMA B-frag
__global__ __launch_bounds__(256) void k_prep2(const float* __restrict__ x,
        const float* __restrict__ wr1, const float* __restrict__ wo1,
        const float* __restrict__ wr2, const float* __restrict__ wo2,
        const float* __restrict__ wr3, const float* __restrict__ wo3,
        unsigned short* __restrict__ xb, unsigned short* __restrict__ wf) {
    int bid = blockIdx.x, t = threadIdx.x;
    if (bid < 5000) {
        int i = bid * 256 + t;                  // N_NODES*16 float4s
        float4 v = ((const float4*)x)[i];
        ushort4 o;
        o.x = f2bf(v.x); o.y = f2bf(v.y); o.z = f2bf(v.z); o.w = f2bf(v.w);
        ((ushort4*)xb)[i] = o;
    } else {
        int idx = (bid - 5000) * 256 + t;       // < 3*8192
        int j = idx & 7, lane = (idx >> 3) & 63;
        int ks = (idx >> 9) & 3, nt = (idx >> 11) & 3, l = idx >> 13;
        int k = ks * 32 + ((lane >> 4) & 3) * 8 + j;
        int n = nt * 16 + (lane & 15);
        const float* wr = (l == 0) ? wr1 : (l == 1) ? wr2 : wr3;
        const float* wo = (l == 0) ? wo1 : (l == 1) ? wo2 : wo3;
        float val = (k < 64) ? wr[n * 64 + k] : wo[n * 64 + (k - 64)];
        wf[idx] = f2bf(val);
    }
}

// ---------- fused bucket aggregation: LDS fp32 accumulators, src-sorted edges
// accum layout channel-permuted: even ch at [0..31], odd ch at [32..63]
// -> each lane's two ds_add_f32 hit its own bank (conflict-free)
__global__ __launch_bounds__(256) void k_gacc(const unsigned short* __restrict__ Xbf,
        const int* __restrict__ bucketbase, const int* __restrict__ ebuf2,
        unsigned short* __restrict__ agg) {
    __shared__ float accum[8192];     // 128 nodes x 64 ch, 32 KB
    __shared__ int ebloc[1024];
    const unsigned* Xu = (const unsigned*)Xbf;
    int b = blockIdx.x, t = threadIdx.x;
    int s = bucketbase[b], e = bucketbase[b + 1], n = e - s;
    for (int i = t; i < 8192; i += 256) accum[i] = 0.f;
    int hw = t >> 5, c = t & 31;
    for (int base = 0; base < n; base += 1024) {
        int m = n - base; if (m > 1024) m = 1024;
        __syncthreads();
        for (int i = t; i < m; i += 256) ebloc[i] = ebuf2[s + base + i];
        __syncthreads();
        for (int sub = hw * 8; sub < m; sub += 64) {
            unsigned v[8]; int dl[8];
            int lim = m - sub;
#pragma unroll
            for (int j = 0; j < 8; ++j) {
                if (j < lim) {
                    int pk = ebloc[sub + j];
                    dl[j] = pk >> 17;
                    v[j] = Xu[(size_t)(pk & 0x1FFFF) * 32 + c];
                } else { dl[j] = -1; v[j] = 0; }
            }
#pragma unroll
            for (int j = 0; j < 8; ++j) {
                if (dl[j] >= 0) {
                    atomicAdd(&accum[dl[j] * 64 + c], bf_lo(v[j]));
                    atomicAdd(&accum[dl[j] * 64 + 32 + c], bf_hi(v[j]));
                }
            }
        }
    }
    __syncthreads();
    unsigned* au = (unsigned*)agg;
    for (int i = t; i < 4096; i += 256) {
        int r = i >> 5, cc = i & 31;
        float lo = accum[r * 64 + cc], hi = accum[r * 64 + 32 + cc];
        au[((size_t)(b * 128 + r)) * 32 + cc] =
            (unsigned)f2bf(lo) | ((unsigned)f2bf(hi) << 16);
    }
}

// ---------- MFMA linear: out = act([agg|x] @ W + b), bf16 in/out, no LDS
__global__ __launch_bounds__(256) void k_linear_mfma(
        const unsigned short* __restrict__ aggb, const unsigned short* __restrict__ xb,
        const unsigned short* __restrict__ wf, const float* __restrict__ bias,
        unsigned short* __restrict__ out, int relu) {
    int t = threadIdx.x, w = t >> 6, lane = t & 63;
    int quad = lane >> 4, l15 = lane & 15;
    int mbase = blockIdx.x * 64 + w * 16;
    size_t arow = (size_t)(mbase + l15) * 64;
    short8f a0 = *(const short8f*)(aggb + arow + quad * 8);
    short8f a1 = *(const short8f*)(aggb + arow + 32 + quad * 8);
    short8f a2 = *(const short8f*)(xb   + arow + quad * 8);
    short8f a3 = *(const short8f*)(xb   + arow + 32 + quad * 8);
    int orow = mbase + quad * 4;
#pragma unroll
    for (int nt = 0; nt < 4; ++nt) {
        const unsigned short* wp = wf + ((size_t)(nt * 4) * 64 + lane) * 8;
        short8f b0 = *(const short8f*)(wp);
        short8f b1 = *(const short8f*)(wp + 64 * 8);
        short8f b2 = *(const short8f*)(wp + 128 * 8);
        short8f b3 = *(const short8f*)(wp + 192 * 8);
        float4f acc = {0.f, 0.f, 0.f, 0.f};
        acc = __builtin_amdgcn_mfma_f32_16x16x32_bf16(a0, b0, acc, 0, 0, 0);
        acc = __builtin_amdgcn_mfma_f32_16x16x32_bf16(a1, b1, acc, 0, 0, 0);
        acc = __builtin_amdgcn_mfma_f32_16x16x32_bf16(a2, b2, acc, 0, 0, 0);
        acc = __builtin_amdgcn_mfma_f32_16x16x32_bf16(a3, b3, acc, 0, 0, 0);
        float bi = bias[nt * 16 + l15];
#pragma unroll
        for (int r = 0; r < 4; ++r) {
            float v = acc[r] + bi;
            if (relu) v = fmaxf(v, 0.f);
            out[(size_t)(orow + r) * 64 + nt * 16 + l15] = f2bf(v);
        }
    }
}

// ---------- fused mean pool + linear head ----------
static __device__ __forceinline__ int lowerb(const int* a, int n, int key) {
    int lo = 0, hi = n;
    while (lo < hi) { int mid = (lo + hi) >> 1; if (a[mid] < key) lo = mid + 1; else hi = mid; }
    return lo;
}

__global__ __launch_bounds__(256) void k_poolhead(const unsigned short* __restrict__ h,
        const int* __restrict__ batch, const float* __restrict__ wlin,
        const float* __restrict__ blin, float* __restrict__ out) {
    __shared__ float sp[8][64];
    int gph = blockIdx.x;
    int t = threadIdx.x, sub = t >> 5, c = t & 31;
    int start = lowerb(batch, N_NODES, gph);
    int end   = lowerb(batch, N_NODES, gph + 1);
    const unsigned* hu = (const unsigned*)h;
    float alo = 0.f, ahi = 0.f;
    for (int i = start + sub; i < end; i += 8) {
        unsigned v = hu[(size_t)i * 32 + c];
        alo += bf_lo(v); ahi += bf_hi(v);
    }
    sp[sub][2 * c] = alo; sp[sub][2 * c + 1] = ahi;
    __syncthreads();
    if (t < 64) {          // wave 0 only
        float v = 0.f;
#pragma unroll
        for (int s = 0; s < 8; ++s) v += sp[s][t];
        int cnt = end - start;
        v /= (float)((cnt > 0) ? cnt : 1);
        float myout = 0.f;
        for (int cls = 0; cls < NCLS; ++cls) {
            float vv = v * wlin[cls * 64 + t];
            for (int off = 32; off > 0; off >>= 1) vv += __shfl_xor(vv, off);
            if (t == cls) myout = vv + blin[cls];
        }
        if (t < NCLS) out[gph * NCLS + t] = myout;
    }
}

extern "C" void kernel_launch(void* const* d_in, const int* in_sizes, int n_in,
                              void* d_out, int out_size, void* d_ws, size_t ws_size,
                              hipStream_t stream) {
    const float* x     = (const float*)d_in[0];
    const int*   ei    = (const int*)d_in[1];
    const int*   batch = (const int*)d_in[2];
    const float* wr1 = (const float*)d_in[3];
    const float* b1  = (const float*)d_in[4];
    const float* wo1 = (const float*)d_in[5];
    const float* wr2 = (const float*)d_in[6];
    const float* b2  = (const float*)d_in[7];
    const float* wo2 = (const float*)d_in[8];
    const float* wr3 = (const float*)d_in[9];
    const float* b3  = (const float*)d_in[10];
    const float* wo3 = (const float*)d_in[11];
    const float* wlin = (const float*)d_in[12];
    const float* blin = (const float*)d_in[13];
    float* out = (float*)d_out;

    char* p = (char*)d_ws;
    auto alloc = [&](size_t bytes) { char* r = p; p += (bytes + 255) & ~(size_t)255; return r; };
    int*   hmat    = (int*)alloc((size_t)NTILE * CBPAD * sizeof(int));
    int*   obase   = (int*)alloc((size_t)NTILE * CBPAD * sizeof(int));
    int*   btot    = (int*)alloc(CBPAD * sizeof(int));
    int*   bucketbase = (int*)alloc((NCB + 1) * sizeof(int));
    int*   ebuf    = (int*)alloc((size_t)N_EDGES * sizeof(int));
    int*   ebuf2   = (int*)alloc((size_t)N_EDGES * sizeof(int));
    unsigned short* wf  = (unsigned short*)alloc(3 * 8192 * sizeof(unsigned short));
    unsigned short* xbf = (unsigned short*)alloc((size_t)N_NODES * 64 * 2);
    unsigned short* agg = (unsigned short*)alloc((size_t)N_NODES * 64 * 2);
    unsigned short* hA  = (unsigned short*)alloc((size_t)N_NODES * 64 * 2);
    unsigned short* hB  = (unsigned short*)alloc((size_t)N_NODES * 64 * 2);

    // CSR-free build: bucket counting sort + within-bucket src sort
    k_hist   <<<NTILE, 256, 0, stream>>>(ei, hmat);
    k_scanT  <<<NCB,   256, 0, stream>>>(hmat, obase, btot);
    k_scanB  <<<1,     256, 0, stream>>>(btot, bucketbase);
    k_scatter<<<NTILE, 256, 0, stream>>>(ei, obase, bucketbase, ebuf);
    k_sortb  <<<NCB,   256, 0, stream>>>(ebuf, bucketbase, ebuf2);
    k_prep2  <<<5096,  256, 0, stream>>>(x, wr1, wo1, wr2, wo2, wr3, wo3, xbf, wf);

    // layer 1
    k_gacc       <<<NCB,          256, 0, stream>>>(xbf, bucketbase, ebuf2, agg);
    k_linear_mfma<<<N_NODES / 64, 256, 0, stream>>>(agg, xbf, wf,         b1, hA, 1);
    // layer 2
    k_gacc       <<<NCB,          256, 0, stream>>>(hA, bucketbase, ebuf2, agg);
    k_linear_mfma<<<N_NODES / 64, 256, 0, stream>>>(agg, hA, wf + 8192,   b2, hB, 1);
    // layer 3
    k_gacc       <<<NCB,          256, 0, stream>>>(hB, bucketbase, ebuf2, agg);
    k_linear_mfma<<<N_NODES / 64, 256, 0, stream>>>(agg, hB, wf + 16384,  b3, hA, 0);

    // pool + head (fused)
    k_poolhead<<<N_GRAPHS, 256, 0, stream>>>(hA, batch, wlin, blin, out);
}

// Round 10
// 277.416 us; speedup vs baseline: 6.4331x; 6.4331x over previous
//
#include <hip/hip_runtime.h>

#define N_NODES  80000
#define N_EDGES  1280000
#define N_GRAPHS 512
#define DIM      64
#define NCLS     10

#define ETILE    8192
#define NTILE    157      // ceil(N_EDGES / ETILE)
#define NCB      157      // ceil(N_NODES / 512) coarse buckets of 512 nodes
#define CBPAD    160

typedef short short8f __attribute__((ext_vector_type(8)));   // 8 bf16 (4 VGPRs)
typedef float float4f __attribute__((ext_vector_type(4)));   // 4 fp32 acc

static __device__ __forceinline__ unsigned short f2bf(float f) {
    unsigned u = __float_as_uint(f);
    unsigned r = (u + 0x7FFFu + ((u >> 16) & 1u)) >> 16;   // RNE
    return (unsigned short)r;
}
static __device__ __forceinline__ float bf_lo(unsigned v) { return __uint_as_float(v << 16); }
static __device__ __forceinline__ float bf_hi(unsigned v) { return __uint_as_float(v & 0xFFFF0000u); }

// ---------- Pass A: per-tile histogram over coarse buckets (no global atomics)
__global__ __launch_bounds__(256) void k_hist(const int* __restrict__ ei,
                                              int* __restrict__ hmat) {
    __shared__ int hist[NCB];
    int tile = blockIdx.x, t = threadIdx.x;
    for (int i = t; i < NCB; i += 256) hist[i] = 0;
    __syncthreads();
    int base = tile * ETILE;
    int end = base + ETILE; if (end > N_EDGES) end = N_EDGES;
    for (int i = base + t; i < end; i += 256)
        atomicAdd(&hist[ei[N_EDGES + i] >> 9], 1);
    __syncthreads();
    for (int i = t; i < NCB; i += 256) hmat[tile * CBPAD + i] = hist[i];
}

// ---------- Pass B1: per-bucket scan across tiles -> within-bucket offsets
__global__ __launch_bounds__(256) void k_scanT(const int* __restrict__ hmat,
        int* __restrict__ obase, int* __restrict__ btot) {
    __shared__ int sa[256], sb[256];
    int b = blockIdx.x, t = threadIdx.x;
    int v = (t < NTILE) ? hmat[t * CBPAD + b] : 0;
    sa[t] = v; __syncthreads();
    int* sp = sa; int* dp = sb;
    for (int off = 1; off < 256; off <<= 1) {
        dp[t] = sp[t] + ((t >= off) ? sp[t - off] : 0);
        __syncthreads();
        int* tmp = sp; sp = dp; dp = tmp;
    }
    int incl = sp[t];
    if (t < NTILE) obase[t * CBPAD + b] = incl - v;
    if (t == NTILE - 1) btot[b] = incl;
}

// ---------- Pass B2: scan bucket totals -> bucket bases
__global__ __launch_bounds__(256) void k_scanB(const int* __restrict__ btot,
        int* __restrict__ bucketbase, int* __restrict__ rowptr) {
    __shared__ int sa[256], sb[256];
    int t = threadIdx.x;
    int v = (t < NCB) ? btot[t] : 0;
    sa[t] = v; __syncthreads();
    int* sp = sa; int* dp = sb;
    for (int off = 1; off < 256; off <<= 1) {
        dp[t] = sp[t] + ((t >= off) ? sp[t - off] : 0);
        __syncthreads();
        int* tmp = sp; sp = dp; dp = tmp;
    }
    int incl = sp[t];
    if (t < NCB) bucketbase[t] = incl - v;
    if (t == 0) { bucketbase[NCB] = N_EDGES; rowptr[N_NODES] = N_EDGES; }
}

// ---------- Pass C: scatter into bucket-sorted ebuf (deterministic runs)
__global__ __launch_bounds__(256) void k_scatter(const int* __restrict__ ei,
        const int* __restrict__ obase, const int* __restrict__ bucketbase,
        int* __restrict__ ebuf) {
    __shared__ int cur[NCB];
    int tile = blockIdx.x, t = threadIdx.x;
    for (int i = t; i < NCB; i += 256)
        cur[i] = bucketbase[i] + obase[tile * CBPAD + i];
    __syncthreads();
    int base = tile * ETILE;
    int end = base + ETILE; if (end > N_EDGES) end = N_EDGES;
    for (int i = base + t; i < end; i += 256) {
        int s = ei[i], d = ei[N_EDGES + i];
        int p = atomicAdd(&cur[d >> 9], 1);
        ebuf[p] = s | ((d & 511) << 17);   // src:17 bits, local dst:9 bits
    }
}

// ---------- Pass D: per-bucket node-level CSR, all in LDS
__global__ __launch_bounds__(256) void k_csr(const int* __restrict__ ebuf,
        const int* __restrict__ bucketbase, int* __restrict__ rowptr,
        int* __restrict__ col) {
    __shared__ int cnt[512];
    __shared__ int sa[512], sb[512];
    __shared__ int cur[512];
    int b = blockIdx.x, t = threadIdx.x;
    int s = bucketbase[b], e = bucketbase[b + 1];
    cnt[t] = 0; cnt[t + 256] = 0;
    __syncthreads();
    for (int i = s + t; i < e; i += 256) atomicAdd(&cnt[ebuf[i] >> 17], 1);
    __syncthreads();
    sa[t] = cnt[t]; sa[t + 256] = cnt[t + 256];
    __syncthreads();
    int* sp = sa; int* dp = sb;
    for (int off = 1; off < 512; off <<= 1) {
        int i1 = t + 256;
        int v0 = sp[t]  + ((t  >= off) ? sp[t  - off] : 0);
        int v1 = sp[i1] + ((i1 >= off) ? sp[i1 - off] : 0);
        __syncthreads();
        dp[t] = v0; dp[i1] = v1;
        __syncthreads();
        int* tmp = sp; sp = dp; dp = tmp;
    }
    int node0 = b * 512;
    int base0 = s + sp[t] - cnt[t];
    int base1 = s + sp[t + 256] - cnt[t + 256];
    cur[t] = base0; cur[t + 256] = base1;
    if (node0 + t < N_NODES)       rowptr[node0 + t] = base0;
    if (node0 + t + 256 < N_NODES) rowptr[node0 + t + 256] = base1;
    __syncthreads();
    for (int i = s + t; i < e; i += 256) {
        int pk = ebuf[i];
        int p = atomicAdd(&cur[pk >> 17], 1);
        col[p] = pk & 0x1FFFF;
    }
}

// ---------- prep: cast x -> bf16 (blocks 0..4999) + pack W into MFMA B-frag
// order bf16 (blocks 5000..5095). wf[l][nt][ks][lane][j]: k=ks*32+quad*8+j,
// n=nt*16+(lane&15); W[k][n] = k<64 ? wrel[n][k] : wroot[n][k-64].
__global__ __launch_bounds__(256) void k_prep2(const float* __restrict__ x,
        const float* __restrict__ wr1, const float* __restrict__ wo1,
        const float* __restrict__ wr2, const float* __restrict__ wo2,
        const float* __restrict__ wr3, const float* __restrict__ wo3,
        unsigned short* __restrict__ xb, unsigned short* __restrict__ wf) {
    int bid = blockIdx.x, t = threadIdx.x;
    if (bid < 5000) {
        int i = bid * 256 + t;                  // N_NODES*16 float4s
        float4 v = ((const float4*)x)[i];
        ushort4 o;
        o.x = f2bf(v.x); o.y = f2bf(v.y); o.z = f2bf(v.z); o.w = f2bf(v.w);
        ((ushort4*)xb)[i] = o;
    } else {
        int idx = (bid - 5000) * 256 + t;       // < 3*8192
        int j = idx & 7, lane = (idx >> 3) & 63;
        int ks = (idx >> 9) & 3, nt = (idx >> 11) & 3, l = idx >> 13;
        int k = ks * 32 + ((lane >> 4) & 3) * 8 + j;
        int n = nt * 16 + (lane & 15);
        const float* wr = (l == 0) ? wr1 : (l == 1) ? wr2 : wr3;
        const float* wo = (l == 0) ? wo1 : (l == 1) ? wo2 : wo3;
        float val = (k < 64) ? wr[n * 64 + k] : wo[n * 64 + (k - 64)];
        wf[idx] = f2bf(val);
    }
}

// ---------- aggregation over bf16 rows: 2 nodes/wave, lane=dword
// main loop unroll 16 (32 rows in flight per wave), tail 4 + scalar
__global__ __launch_bounds__(256) void k_gather_bf(const unsigned short* __restrict__ Xbf,
        const int* __restrict__ rowptr, const int* __restrict__ col,
        unsigned short* __restrict__ agg) {
    const unsigned* Xu = (const unsigned*)Xbf;
    int t = threadIdx.x, w = t >> 6, lane = t & 63;
    int g = lane >> 5, c = lane & 31;
    int node = blockIdx.x * 8 + w * 2 + g;
    int start = rowptr[node], end = rowptr[node + 1];
    float alo = 0.f, ahi = 0.f;
    int e = start;
    for (; e + 16 <= end; e += 16) {
        unsigned v[16];
#pragma unroll
        for (int j = 0; j < 16; ++j)
            v[j] = Xu[(size_t)col[e + j] * 32 + c];
#pragma unroll
        for (int j = 0; j < 16; ++j) { alo += bf_lo(v[j]); ahi += bf_hi(v[j]); }
    }
    for (; e + 4 <= end; e += 4) {
        unsigned v0 = Xu[(size_t)col[e]     * 32 + c];
        unsigned v1 = Xu[(size_t)col[e + 1] * 32 + c];
        unsigned v2 = Xu[(size_t)col[e + 2] * 32 + c];
        unsigned v3 = Xu[(size_t)col[e + 3] * 32 + c];
        alo += (bf_lo(v0) + bf_lo(v1)) + (bf_lo(v2) + bf_lo(v3));
        ahi += (bf_hi(v0) + bf_hi(v1)) + (bf_hi(v2) + bf_hi(v3));
    }
    for (; e < end; ++e) {
        unsigned v = Xu[(size_t)col[e] * 32 + c];
        alo += bf_lo(v); ahi += bf_hi(v);
    }
    unsigned o = (unsigned)f2bf(alo) | ((unsigned)f2bf(ahi) << 16);
    ((unsigned*)agg)[(size_t)node * 32 + c] = o;
}

// ---------- MFMA linear: out = act([agg|x] @ W + b), bf16 in/out, no LDS
// wave = 16 nodes x 64 outch; A direct from global (A[m=lane&15][k=quad*8+j]);
// B pre-packed frags; D: col=lane&15, row=quad*4+reg (m89-verified).
__global__ __launch_bounds__(256) void k_linear_mfma(
        const unsigned short* __restrict__ aggb, const unsigned short* __restrict__ xb,
        const unsigned short* __restrict__ wf, const float* __restrict__ bias,
        unsigned short* __restrict__ out, int relu) {
    int t = threadIdx.x, w = t >> 6, lane = t & 63;
    int quad = lane >> 4, l15 = lane & 15;
    int mbase = blockIdx.x * 64 + w * 16;
    size_t arow = (size_t)(mbase + l15) * 64;
    short8f a0 = *(const short8f*)(aggb + arow + quad * 8);
    short8f a1 = *(const short8f*)(aggb + arow + 32 + quad * 8);
    short8f a2 = *(const short8f*)(xb   + arow + quad * 8);
    short8f a3 = *(const short8f*)(xb   + arow + 32 + quad * 8);
    int orow = mbase + quad * 4;
#pragma unroll
    for (int nt = 0; nt < 4; ++nt) {
        const unsigned short* wp = wf + ((size_t)(nt * 4) * 64 + lane) * 8;
        short8f b0 = *(const short8f*)(wp);
        short8f b1 = *(const short8f*)(wp + 64 * 8);
        short8f b2 = *(const short8f*)(wp + 128 * 8);
        short8f b3 = *(const short8f*)(wp + 192 * 8);
        float4f acc = {0.f, 0.f, 0.f, 0.f};
        acc = __builtin_amdgcn_mfma_f32_16x16x32_bf16(a0, b0, acc, 0, 0, 0);
        acc = __builtin_amdgcn_mfma_f32_16x16x32_bf16(a1, b1, acc, 0, 0, 0);
        acc = __builtin_amdgcn_mfma_f32_16x16x32_bf16(a2, b2, acc, 0, 0, 0);
        acc = __builtin_amdgcn_mfma_f32_16x16x32_bf16(a3, b3, acc, 0, 0, 0);
        float bi = bias[nt * 16 + l15];
#pragma unroll
        for (int r = 0; r < 4; ++r) {
            float v = acc[r] + bi;
            if (relu) v = fmaxf(v, 0.f);
            out[(size_t)(orow + r) * 64 + nt * 16 + l15] = f2bf(v);
        }
    }
}

// ---------- fused mean pool + linear head ----------
static __device__ __forceinline__ int lowerb(const int* a, int n, int key) {
    int lo = 0, hi = n;
    while (lo < hi) { int mid = (lo + hi) >> 1; if (a[mid] < key) lo = mid + 1; else hi = mid; }
    return lo;
}

__global__ __launch_bounds__(256) void k_poolhead(const unsigned short* __restrict__ h,
        const int* __restrict__ batch, const float* __restrict__ wlin,
        const float* __restrict__ blin, float* __restrict__ out) {
    __shared__ float sp[8][64];
    int gph = blockIdx.x;
    int t = threadIdx.x, sub = t >> 5, c = t & 31;
    int start = lowerb(batch, N_NODES, gph);
    int end   = lowerb(batch, N_NODES, gph + 1);
    const unsigned* hu = (const unsigned*)h;
    float alo = 0.f, ahi = 0.f;
    for (int i = start + sub; i < end; i += 8) {
        unsigned v = hu[(size_t)i * 32 + c];
        alo += bf_lo(v); ahi += bf_hi(v);
    }
    sp[sub][2 * c] = alo; sp[sub][2 * c + 1] = ahi;
    __syncthreads();
    if (t < 64) {          // wave 0 only
        float v = 0.f;
#pragma unroll
        for (int s = 0; s < 8; ++s) v += sp[s][t];
        int cnt = end - start;
        v /= (float)((cnt > 0) ? cnt : 1);
        float myout = 0.f;
        for (int cls = 0; cls < NCLS; ++cls) {
            float vv = v * wlin[cls * 64 + t];
            for (int off = 32; off > 0; off >>= 1) vv += __shfl_xor(vv, off);
            if (t == cls) myout = vv + blin[cls];
        }
        if (t < NCLS) out[gph * NCLS + t] = myout;
    }
}

extern "C" void kernel_launch(void* const* d_in, const int* in_sizes, int n_in,
                              void* d_out, int out_size, void* d_ws, size_t ws_size,
                              hipStream_t stream) {
    const float* x     = (const float*)d_in[0];
    const int*   ei    = (const int*)d_in[1];
    const int*   batch = (const int*)d_in[2];
    const float* wr1 = (const float*)d_in[3];
    const float* b1  = (const float*)d_in[4];
    const float* wo1 = (const float*)d_in[5];
    const float* wr2 = (const float*)d_in[6];
    const float* b2  = (const float*)d_in[7];
    const float* wo2 = (const float*)d_in[8];
    const float* wr3 = (const float*)d_in[9];
    const float* b3  = (const float*)d_in[10];
    const float* wo3 = (const float*)d_in[11];
    const float* wlin = (const float*)d_in[12];
    const float* blin = (const float*)d_in[13];
    float* out = (float*)d_out;

    char* p = (char*)d_ws;
    auto alloc = [&](size_t bytes) { char* r = p; p += (bytes + 255) & ~(size_t)255; return r; };
    int*   rowptr  = (int*)alloc((N_NODES + 1) * sizeof(int));
    int*   hmat    = (int*)alloc((size_t)NTILE * CBPAD * sizeof(int));
    int*   obase   = (int*)alloc((size_t)NTILE * CBPAD * sizeof(int));
    int*   btot    = (int*)alloc(CBPAD * sizeof(int));
    int*   bucketbase = (int*)alloc((NCB + 1) * sizeof(int));
    int*   ebuf    = (int*)alloc((size_t)N_EDGES * sizeof(int));
    int*   col     = (int*)alloc((size_t)N_EDGES * sizeof(int));
    unsigned short* wf  = (unsigned short*)alloc(3 * 8192 * sizeof(unsigned short));
    unsigned short* xbf = (unsigned short*)alloc((size_t)N_NODES * 64 * 2);
    unsigned short* agg = (unsigned short*)alloc((size_t)N_NODES * 64 * 2);
    unsigned short* hA  = (unsigned short*)alloc((size_t)N_NODES * 64 * 2);
    unsigned short* hB  = (unsigned short*)alloc((size_t)N_NODES * 64 * 2);

    // CSR build: deterministic two-level counting sort, zero global atomics
    k_hist   <<<NTILE, 256, 0, stream>>>(ei, hmat);
    k_scanT  <<<NCB,   256, 0, stream>>>(hmat, obase, btot);
    k_scanB  <<<1,     256, 0, stream>>>(btot, bucketbase, rowptr);
    k_scatter<<<NTILE, 256, 0, stream>>>(ei, obase, bucketbase, ebuf);
    k_csr    <<<NCB,   256, 0, stream>>>(ebuf, bucketbase, rowptr, col);
    k_prep2  <<<5096,  256, 0, stream>>>(x, wr1, wo1, wr2, wo2, wr3, wo3, xbf, wf);

    // layer 1
    k_gather_bf  <<<N_NODES / 8,  256, 0, stream>>>(xbf, rowptr, col, agg);
    k_linear_mfma<<<N_NODES / 64, 256, 0, stream>>>(agg, xbf, wf,         b1, hA, 1);
    // layer 2
    k_gather_bf  <<<N_NODES / 8,  256, 0, stream>>>(hA, rowptr, col, agg);
    k_linear_mfma<<<N_NODES / 64, 256, 0, stream>>>(agg, hA, wf + 8192,   b2, hB, 1);
    // layer 3
    k_gather_bf  <<<N_NODES / 8,  256, 0, stream>>>(hB, rowptr, col, agg);
    k_linear_mfma<<<N_NODES / 64, 256, 0, stream>>>(agg, hB, wf + 16384,  b3, hA, 0);

    // pool + head (fused)
    k_poolhead<<<N_GRAPHS, 256, 0, stream>>>(hA, batch, wlin, blin, out);
}